// Round 4
// baseline (72.272 us; speedup 1.0000x reference)
//
#include <hip/hip_runtime.h>

#define MEMN 262144
#define DIM 128
#define BS 256
#define NPOS 8
#define NNEG 1024
#define KTOT 1033                 /* 1 + NPOS + NNEG */
#define NK (BS * KTOT)            /* 264448 entries */
#define NBKT 2048
#define BSHIFT 7                  /* bucket = idx >> 7 : 128 rows / 64KB windows */
#define CAP 320                   /* Poisson(129); P(>320) ~ 1e-24 */
#define CSTRIDE 16                /* one counter per 64B line */
#define TSCALE 14.285714285714286f

/* ---- d_ws layout ----
   qbuf   : float[2][BS][DIM]   @ 0        (256 KB)  [0]=video-norm/T, [1]=audio-norm/T
   counts : int[NBKT*CSTRIDE]   @ 262144   (128 KB)
   entries: uint2[NBKT*CAP]     @ 393216   (5 MB)
*/
#define COUNTS_OFF 262144
#define ENTRIES_OFF 393216

__global__ __launch_bounds__(256) void prep_kernel(
    const float* __restrict__ video, const float* __restrict__ audio,
    float* __restrict__ qbuf, int* __restrict__ counts)
{
    const int t = blockIdx.x * 256 + threadIdx.x;   // grid 32 -> t in [0,8192)
    if (t < NBKT) counts[t << 4] = 0;

    const int row = t >> 4;          // 0..511
    const int g   = t & 15;
    const int m   = row >> 8;        // 0: video, 1: audio
    const int b   = row & 255;
    const float* src = (m ? audio : video) + b * DIM + g * 8;

    float4 q0 = *(const float4*)(src);
    float4 q1 = *(const float4*)(src + 4);
    float qq = q0.x*q0.x + q0.y*q0.y + q0.z*q0.z + q0.w*q0.w
             + q1.x*q1.x + q1.y*q1.y + q1.z*q1.z + q1.w*q1.w;
    qq += __shfl_xor(qq, 1);
    qq += __shfl_xor(qq, 2);
    qq += __shfl_xor(qq, 4);
    qq += __shfl_xor(qq, 8);
    const float scale = TSCALE / fmaxf(sqrtf(qq), 1e-12f);
    q0.x *= scale; q0.y *= scale; q0.z *= scale; q0.w *= scale;
    q1.x *= scale; q1.y *= scale; q1.z *= scale; q1.w *= scale;

    float* dst = qbuf + (size_t)row * DIM + g * 8;
    *(float4*)(dst)     = q0;
    *(float4*)(dst + 4) = q1;
}

__global__ __launch_bounds__(256) void scatter_kernel(
    const int* __restrict__ y, const int* __restrict__ pos,
    const int* __restrict__ neg, int* __restrict__ counts,
    uint2* __restrict__ entries)
{
    const int b = blockIdx.x;        // grid 256
    for (int k = threadIdx.x; k < KTOT; k += 256) {
        int idx;
        if (k == 0)          idx = y[b];
        else if (k <= NPOS)  idx = pos[b * NPOS + (k - 1)];
        else                 idx = neg[b * NNEG + (k - 1 - NPOS)];
        const int bkt = idx >> BSHIFT;
        const int slot = atomicAdd(&counts[bkt << 4], 1);
        if (slot < CAP)
            entries[bkt * CAP + slot] = make_uint2((unsigned)idx,
                                                   ((unsigned)b << 11) | (unsigned)k);
    }
}

__global__ __launch_bounds__(256) void compute_kernel(
    const float* __restrict__ view1, const float* __restrict__ view2,
    const float* __restrict__ qbuf, const int* __restrict__ counts,
    const uint2* __restrict__ entries, float* __restrict__ out)
{
    const int bkt = blockIdx.x;      // grid NBKT
    int cnt = counts[bkt << 4];
    if (cnt > CAP) cnt = CAP;
    const int g   = threadIdx.x & 15;
    const int grp = threadIdx.x >> 4;
    const uint2* ebase = entries + (size_t)bkt * CAP;

    for (int i = grp; i < cnt; i += 16) {
        const uint2 e = ebase[i];
        const int idx = (int)e.x;
        const int b   = (int)(e.y >> 11);
        const int k   = (int)(e.y & 2047u);

        const float* r2 = view2 + (size_t)idx * DIM + g * 8;   // for v2a
        const float* r1 = view1 + (size_t)idx * DIM + g * 8;   // for a2v
        const float* qv = qbuf + (size_t)b * DIM + g * 8;               // video query
        const float* qa = qbuf + (size_t)(BS + b) * DIM + g * 8;        // audio query

        float4 a0 = *(const float4*)(r2);
        float4 a1 = *(const float4*)(r2 + 4);
        float4 b0 = *(const float4*)(r1);
        float4 b1 = *(const float4*)(r1 + 4);
        float4 v0 = *(const float4*)(qv);
        float4 v1 = *(const float4*)(qv + 4);
        float4 u0 = *(const float4*)(qa);
        float4 u1 = *(const float4*)(qa + 4);

        float s0 = a0.x*v0.x + a0.y*v0.y + a0.z*v0.z + a0.w*v0.w
                 + a1.x*v1.x + a1.y*v1.y + a1.z*v1.z + a1.w*v1.w;
        float s1 = b0.x*u0.x + b0.y*u0.y + b0.z*u0.z + b0.w*u0.w
                 + b1.x*u1.x + b1.y*u1.y + b1.z*u1.z + b1.w*u1.w;

        s0 += __shfl_xor(s0, 1);
        s0 += __shfl_xor(s0, 2);
        s0 += __shfl_xor(s0, 4);
        s0 += __shfl_xor(s0, 8);
        s1 += __shfl_xor(s1, 1);
        s1 += __shfl_xor(s1, 2);
        s1 += __shfl_xor(s1, 4);
        s1 += __shfl_xor(s1, 8);

        if (g == 0) {
            out[(size_t)b * KTOT + k] = s0;                     // v2a
            out[(size_t)BS * KTOT + (size_t)b * KTOT + k] = s1; // a2v
        }
    }
}

extern "C" void kernel_launch(void* const* d_in, const int* in_sizes, int n_in,
                              void* d_out, int out_size, void* d_ws, size_t ws_size,
                              hipStream_t stream) {
    const float* video = (const float*)d_in[0];
    const float* audio = (const float*)d_in[1];
    const float* view1 = (const float*)d_in[2];
    const float* view2 = (const float*)d_in[3];
    const int*   y     = (const int*)d_in[4];
    const int*   pos   = (const int*)d_in[5];
    const int*   neg   = (const int*)d_in[6];
    float* out = (float*)d_out;

    char* ws = (char*)d_ws;
    float* qbuf    = (float*)ws;
    int*   counts  = (int*)(ws + COUNTS_OFF);
    uint2* entries = (uint2*)(ws + ENTRIES_OFF);

    prep_kernel<<<32, 256, 0, stream>>>(video, audio, qbuf, counts);
    scatter_kernel<<<BS, 256, 0, stream>>>(y, pos, neg, counts, entries);
    compute_kernel<<<NBKT, 256, 0, stream>>>(view1, view2, qbuf, counts, entries, out);
}